// Round 1
// baseline (911.353 us; speedup 1.0000x reference)
//
#include <hip/hip_runtime.h>
#include <stdint.h>

#define NTOK 98
#define CDIM 96
#define LDK 104   // k/out_attn buffer row stride (elems), 112 rows
#define LDV 136   // vT col count (tokens padded to 128 + 8)
#define LDSCR 40  // per-wave scratch row stride, 32 rows

typedef __bf16 bf16x8 __attribute__((ext_vector_type(8)));
typedef float f32x4 __attribute__((ext_vector_type(4)));

__device__ __forceinline__ uint16_t f2bfbits(float f) {
  uint32_t u = __builtin_bit_cast(uint32_t, f);
  u += 0x7FFFu + ((u >> 16) & 1u);   // RTNE
  return (uint16_t)(u >> 16);
}
__device__ __forceinline__ __bf16 bits2bf(uint16_t h) {
  return __builtin_bit_cast(__bf16, h);
}
__device__ __forceinline__ __bf16 f2bf(float f) { return bits2bf(f2bfbits(f)); }

__device__ __forceinline__ bf16x8 cvt8(const float* p) {
  float4 a = *(const float4*)p;
  float4 b = *(const float4*)(p + 4);
  bf16x8 r;
  r[0] = f2bf(a.x); r[1] = f2bf(a.y); r[2] = f2bf(a.z); r[3] = f2bf(a.w);
  r[4] = f2bf(b.x); r[5] = f2bf(b.y); r[6] = f2bf(b.z); r[7] = f2bf(b.w);
  return r;
}

// One block per window. 4 waves; wave w owns query rows [32w, 32w+32).
// M-tiles padded to 128 rows; rows >= 98 are computed-but-masked garbage.
__global__ __launch_bounds__(256, 2) void wattn3d(
    const float* __restrict__ x, const float* __restrict__ qkv_w,
    const float* __restrict__ qkv_b, const float* __restrict__ proj_w,
    const float* __restrict__ proj_b, const float* __restrict__ bias_table,
    const int* __restrict__ rel_index, float* __restrict__ out) {
  __shared__ __bf16 k_lds[112 * LDK];   // k rows 0..111; later aliased by out_attn
  __shared__ __bf16 vT[CDIM * LDV];     // vT[d][token], tokens 0..127 valid
  __shared__ __bf16 scr[4 * 32 * LDSCR];

  const int tid = threadIdx.x;
  const int wave = tid >> 6;
  const int lane = tid & 63;
  const int quad = lane >> 4;
  const int l16 = lane & 15;
  const int b = blockIdx.x;
  const int rowbase = wave * 32;
  __bf16* myscr = &scr[wave * 32 * LDSCR];

  // zero-fill vT tokens 112..135 (never written by QKV; must be finite/zero)
  for (int i = tid; i < CDIM * 24; i += 256) {
    int d = i / 24, t = 112 + (i % 24);
    vT[d * LDV + t] = bits2bf(0);
  }

  const float* xb = x + (size_t)b * NTOK * CDIM;

  // ---------------- QKV GEMM: [98x96] @ [96x288]^T ----------------
  bf16x8 a_x[2][3];
#pragma unroll
  for (int mt = 0; mt < 2; ++mt) {
    int row = rowbase + mt * 16 + l16;
#pragma unroll
    for (int kt = 0; kt < 3; ++kt) {
      if (row < NTOK) {
        a_x[mt][kt] = cvt8(xb + row * CDIM + kt * 32 + quad * 8);
      } else {
        bf16x8 z;
#pragma unroll
        for (int j = 0; j < 8; ++j) z[j] = bits2bf(0);
        a_x[mt][kt] = z;
      }
    }
  }

  uint32_t qreg[2][6][2];  // q strip kept in registers (packed bf16)
#pragma unroll
  for (int nt = 0; nt < 18; ++nt) {
    bf16x8 bw[3];
#pragma unroll
    for (int kt = 0; kt < 3; ++kt)
      bw[kt] = cvt8(qkv_w + (nt * 16 + l16) * CDIM + kt * 32 + quad * 8);
    float bn = qkv_b[nt * 16 + l16];
#pragma unroll
    for (int mt = 0; mt < 2; ++mt) {
      f32x4 acc = {0.f, 0.f, 0.f, 0.f};
#pragma unroll
      for (int kt = 0; kt < 3; ++kt)
        acc = __builtin_amdgcn_mfma_f32_16x16x32_bf16(a_x[mt][kt], bw[kt], acc, 0, 0, 0);
      uint16_t h4[4];
#pragma unroll
      for (int i = 0; i < 4; ++i) h4[i] = f2bfbits(acc[i] + bn);
      if (nt < 6) {  // q
        qreg[mt][nt][0] = (uint32_t)h4[0] | ((uint32_t)h4[1] << 16);
        qreg[mt][nt][1] = (uint32_t)h4[2] | ((uint32_t)h4[3] << 16);
      } else if (nt < 12) {  // k, row-major
        int colb = (nt - 6) * 16 + l16;
#pragma unroll
        for (int i = 0; i < 4; ++i) {
          int row = rowbase + mt * 16 + quad * 4 + i;
          if (row < 112) k_lds[row * LDK + colb] = bits2bf(h4[i]);
        }
      } else {  // v, transposed: 4 consecutive tokens -> one 8B store
        int d = (nt - 12) * 16 + l16;
        int t0 = rowbase + mt * 16 + quad * 4;
        uint2 pk;
        pk.x = (uint32_t)h4[0] | ((uint32_t)h4[1] << 16);
        pk.y = (uint32_t)h4[2] | ((uint32_t)h4[3] << 16);
        *(uint2*)&vT[d * LDV + t0] = pk;
      }
    }
  }
  __syncthreads();

  // ---------------- attention, head-by-head ----------------
  const float scale = 0.17677669529663687f;  // 32^-0.5
  float rsum[2][4];
  f32x4 oacc[2][2];

#pragma unroll
  for (int h = 0; h < 3; ++h) {
    // q strip (this head's 32 cols) -> per-wave scratch, D-layout -> row-major
#pragma unroll
    for (int mt = 0; mt < 2; ++mt)
#pragma unroll
      for (int nth = 0; nth < 2; ++nth) {
        uint32_t w0 = qreg[mt][2 * h + nth][0];
        uint32_t w1 = qreg[mt][2 * h + nth][1];
        int lr = mt * 16 + quad * 4;
        int cc = nth * 16 + l16;
        myscr[(lr + 0) * LDSCR + cc] = bits2bf((uint16_t)(w0 & 0xffffu));
        myscr[(lr + 1) * LDSCR + cc] = bits2bf((uint16_t)(w0 >> 16));
        myscr[(lr + 2) * LDSCR + cc] = bits2bf((uint16_t)(w1 & 0xffffu));
        myscr[(lr + 3) * LDSCR + cc] = bits2bf((uint16_t)(w1 >> 16));
      }
    asm volatile("s_waitcnt lgkmcnt(0)" ::: "memory");  // wave-local visibility
    bf16x8 aq[2];
#pragma unroll
    for (int mt = 0; mt < 2; ++mt)
      aq[mt] = *(bf16x8*)&myscr[(mt * 16 + l16) * LDSCR + quad * 8];

    // scores: S = q @ k^T, K=32 -> one MFMA per tile; S lives in regs
    f32x4 sacc[2][7];
#pragma unroll
    for (int nt = 0; nt < 7; ++nt) {
      int tok = nt * 16 + l16;
      bf16x8 bk = *(bf16x8*)&k_lds[tok * LDK + h * 32 + quad * 8];
#pragma unroll
      for (int mt = 0; mt < 2; ++mt) {
        f32x4 z = {0.f, 0.f, 0.f, 0.f};
        sacc[mt][nt] = __builtin_amdgcn_mfma_f32_16x16x32_bf16(aq[mt], bk, z, 0, 0, 0);
      }
    }

    // softmax over each row (row lives in the 16 lanes of one quad x 7 regs)
#pragma unroll
    for (int mt = 0; mt < 2; ++mt)
#pragma unroll
      for (int i = 0; i < 4; ++i) {
        int row = rowbase + mt * 16 + quad * 4 + i;
        float mx = -1e30f;
#pragma unroll
        for (int nt = 0; nt < 7; ++nt) {
          int col = nt * 16 + l16;
          float s;
          if (col < NTOK) {
            s = sacc[mt][nt][i] * scale;
            if (row < NTOK) s += bias_table[rel_index[row * NTOK + col] * 3 + h];
          } else {
            s = -1e30f;  // mask padded key columns
          }
          sacc[mt][nt][i] = s;
          mx = fmaxf(mx, s);
        }
#pragma unroll
        for (int d2 = 1; d2 < 16; d2 <<= 1) mx = fmaxf(mx, __shfl_xor(mx, d2));
        float sum = 0.f;
#pragma unroll
        for (int nt = 0; nt < 7; ++nt) {
          float p = __expf(sacc[mt][nt][i] - mx);
          sacc[mt][nt][i] = p;
          sum += p;
        }
#pragma unroll
        for (int d2 = 1; d2 < 16; d2 <<= 1) sum += __shfl_xor(sum, d2);
        rsum[mt][i] = 1.f / sum;
      }

    // PV: out_h = P @ v_h ; P chunks through scratch (D-layout -> A-layout)
#pragma unroll
    for (int mt = 0; mt < 2; ++mt)
#pragma unroll
      for (int nh = 0; nh < 2; ++nh) {
        f32x4 z = {0.f, 0.f, 0.f, 0.f};
        oacc[mt][nh] = z;
      }
#pragma unroll
    for (int kt2 = 0; kt2 < 4; ++kt2) {
#pragma unroll
      for (int half = 0; half < 2; ++half) {
        int ntS = 2 * kt2 + half;
#pragma unroll
        for (int mt = 0; mt < 2; ++mt) {
          int lr = mt * 16 + quad * 4;
          int cc = half * 16 + l16;
#pragma unroll
          for (int i = 0; i < 4; ++i) {
            float v = (ntS < 7) ? sacc[mt][ntS][i] : 0.f;  // tokens>=112 -> 0
            myscr[(lr + i) * LDSCR + cc] = f2bf(v);
          }
        }
      }
      asm volatile("s_waitcnt lgkmcnt(0)" ::: "memory");
#pragma unroll
      for (int mt = 0; mt < 2; ++mt) {
        bf16x8 ap = *(bf16x8*)&myscr[(mt * 16 + l16) * LDSCR + quad * 8];
#pragma unroll
        for (int nh = 0; nh < 2; ++nh) {
          bf16x8 bv = *(bf16x8*)&vT[(h * 32 + nh * 16 + l16) * LDV + kt2 * 32 + quad * 8];
          oacc[mt][nh] = __builtin_amdgcn_mfma_f32_16x16x32_bf16(ap, bv, oacc[mt][nh], 0, 0, 0);
        }
      }
    }

    // write out_h into the (dead) k_h columns. Barrier: all waves must be done
    // reading k cols [32h,32h+32) before they get overwritten.
    __syncthreads();
#pragma unroll
    for (int mt = 0; mt < 2; ++mt)
#pragma unroll
      for (int nh = 0; nh < 2; ++nh)
#pragma unroll
        for (int i = 0; i < 4; ++i) {
          int row = rowbase + mt * 16 + quad * 4 + i;
          if (row < 112)
            k_lds[row * LDK + h * 32 + nh * 16 + l16] =
                f2bf(oacc[mt][nh][i] * rsum[mt][i]);
        }
  }

  // ---------------- proj: [98x96] @ [96x96]^T + b ----------------
  bf16x8 ao[2][3];
#pragma unroll
  for (int mt = 0; mt < 2; ++mt) {
    int arow = rowbase + mt * 16 + l16;
    if (arow >= 112) arow = 0;  // wave3 mt=1 garbage rows; results masked below
#pragma unroll
    for (int kt = 0; kt < 3; ++kt)
      ao[mt][kt] = *(bf16x8*)&k_lds[arow * LDK + kt * 32 + quad * 8];
  }
  float* outb = out + (size_t)b * NTOK * CDIM;
#pragma unroll
  for (int nt = 0; nt < 6; ++nt) {
    bf16x8 bp[3];
#pragma unroll
    for (int kt = 0; kt < 3; ++kt)
      bp[kt] = cvt8(proj_w + (nt * 16 + l16) * CDIM + kt * 32 + quad * 8);
    float pb = proj_b[nt * 16 + l16];
#pragma unroll
    for (int mt = 0; mt < 2; ++mt) {
      f32x4 acc = {0.f, 0.f, 0.f, 0.f};
#pragma unroll
      for (int kt = 0; kt < 3; ++kt)
        acc = __builtin_amdgcn_mfma_f32_16x16x32_bf16(ao[mt][kt], bp[kt], acc, 0, 0, 0);
#pragma unroll
      for (int i = 0; i < 4; ++i) {
        int row = rowbase + mt * 16 + quad * 4 + i;
        if (row < NTOK) outb[row * CDIM + nt * 16 + l16] = acc[i] + pb;
      }
    }
  }
}

extern "C" void kernel_launch(void* const* d_in, const int* in_sizes, int n_in,
                              void* d_out, int out_size, void* d_ws, size_t ws_size,
                              hipStream_t stream) {
  (void)n_in; (void)out_size; (void)d_ws; (void)ws_size;
  const float* x = (const float*)d_in[0];
  const float* qkv_w = (const float*)d_in[1];
  const float* qkv_b = (const float*)d_in[2];
  const float* proj_w = (const float*)d_in[3];
  const float* proj_b = (const float*)d_in[4];
  const float* bias_table = (const float*)d_in[5];
  const int* rel_index = (const int*)d_in[6];
  float* out = (float*)d_out;
  int Bwin = in_sizes[0] / (NTOK * CDIM);
  wattn3d<<<dim3(Bwin), dim3(256), 0, stream>>>(x, qkv_w, qkv_b, proj_w,
                                                proj_b, bias_table, rel_index, out);
}

// Round 2
// 447.253 us; speedup vs baseline: 2.0377x; 2.0377x over previous
//
#include <hip/hip_runtime.h>
#include <stdint.h>

#define NTOK 98
#define CDIM 96
#define LDK 104   // k/out_attn row stride (elems); 98 rows stored, reads may
                  // overflow into vT (finite garbage, masked) by design
#define LDV 120   // vT col count: tokens 0..111 real/junk, 112..119 zeroed,
                  // reads of 120..127 spill into next row * P==0
#define LDSCR 40  // per-wave scratch row stride, 32 rows

typedef __bf16 bf16x8 __attribute__((ext_vector_type(8)));
typedef float f32x4 __attribute__((ext_vector_type(4)));

__device__ __forceinline__ uint16_t f2bfbits(float f) {
  uint32_t u = __builtin_bit_cast(uint32_t, f);
  u += 0x7FFFu + ((u >> 16) & 1u);   // RTNE
  return (uint16_t)(u >> 16);
}
__device__ __forceinline__ __bf16 bits2bf(uint16_t h) {
  return __builtin_bit_cast(__bf16, h);
}
__device__ __forceinline__ __bf16 f2bf(float f) { return bits2bf(f2bfbits(f)); }

__device__ __forceinline__ bf16x8 cvt8(const float* p) {
  float4 a = *(const float4*)p;
  float4 b = *(const float4*)(p + 4);
  bf16x8 r;
  r[0] = f2bf(a.x); r[1] = f2bf(a.y); r[2] = f2bf(a.z); r[3] = f2bf(a.w);
  r[4] = f2bf(b.x); r[5] = f2bf(b.y); r[6] = f2bf(b.z); r[7] = f2bf(b.w);
  return r;
}

// ---------------- precompute: weights -> bf16 fragment order; bias -> dense f32
// qkv_wp layout: [nt(18)][kt(3)][quad(4)][l16(16)][j(8)] bf16
// proj_wp layout: [nt(6)][kt(3)][quad(4)][l16(16)][j(8)] bf16
// bias_full: [h(3)][row(128)][col(112)] f32 (rows>=98 / cols>=98 -> 0)
__global__ void precompute(const float* __restrict__ qkv_w,
                           const float* __restrict__ proj_w,
                           const float* __restrict__ bias_table,
                           const int* __restrict__ rel_index,
                           uint16_t* __restrict__ qkv_wp,
                           uint16_t* __restrict__ proj_wp,
                           float* __restrict__ bias_full) {
  int t = blockIdx.x * blockDim.x + threadIdx.x;
  int stride = gridDim.x * blockDim.x;
  for (int f = t; f < 18 * 3 * 4 * 16 * 8; f += stride) {
    int j = f & 7, l16 = (f >> 3) & 15, quad = (f >> 7) & 3, ktnt = f >> 9;
    int kt = ktnt % 3, nt = ktnt / 3;
    qkv_wp[f] = f2bfbits(qkv_w[(nt * 16 + l16) * CDIM + kt * 32 + quad * 8 + j]);
  }
  for (int f = t; f < 6 * 3 * 4 * 16 * 8; f += stride) {
    int j = f & 7, l16 = (f >> 3) & 15, quad = (f >> 7) & 3, ktnt = f >> 9;
    int kt = ktnt % 3, nt = ktnt / 3;
    proj_wp[f] = f2bfbits(proj_w[(nt * 16 + l16) * CDIM + kt * 32 + quad * 8 + j]);
  }
  for (int f = t; f < 3 * 128 * 112; f += stride) {
    int col = f % 112;
    int hr = f / 112;
    int row = hr & 127;
    int h = hr >> 7;
    float v = 0.f;
    if (row < NTOK && col < NTOK)
      v = bias_table[rel_index[row * NTOK + col] * 3 + h];
    bias_full[f] = v;
  }
}

// One block per window. 4 waves; wave w owns query rows [32w, 32w+32).
__global__ __launch_bounds__(256, 3) void wattn3d(
    const float* __restrict__ x, const float* __restrict__ qkv_b,
    const float* __restrict__ proj_b, const uint16_t* __restrict__ qkv_wp,
    const uint16_t* __restrict__ proj_wp, const float* __restrict__ bias_full,
    float* __restrict__ out) {
  // manual LDS layout: k_lds 20384 B | vT 23040 B | scr 10240 B = 53664 B
  __shared__ __align__(16) char smem[53664];
  __bf16* k_lds = (__bf16*)smem;                 // 98 rows x LDK
  __bf16* vT = (__bf16*)(smem + 20384);          // 96 rows x LDV
  __bf16* scr = (__bf16*)(smem + 43424);         // 4 waves x 32 x LDSCR

  const int tid = threadIdx.x;
  const int wave = tid >> 6;
  const int lane = tid & 63;
  const int quad = lane >> 4;
  const int l16 = lane & 15;
  const int b = blockIdx.x;
  const int rowbase = wave * 32;
  __bf16* myscr = &scr[wave * 32 * LDSCR];
  const float scale = 0.17677669529663687f;  // 32^-0.5

  // zero-fill vT tokens 112..119 (pad region read by PV tail)
  for (int i = tid; i < CDIM * 8; i += 256) {
    int d = i >> 3, tk = 112 + (i & 7);
    vT[d * LDV + tk] = bits2bf(0);
  }

  const float* xb = x + (size_t)b * NTOK * CDIM;

  // ---------------- QKV GEMM: [98x96] @ [96x288]^T ----------------
  bf16x8 a_x[2][3];
#pragma unroll
  for (int mt = 0; mt < 2; ++mt) {
    int row = rowbase + mt * 16 + l16;
#pragma unroll
    for (int kt = 0; kt < 3; ++kt) {
      if (row < NTOK) {
        a_x[mt][kt] = cvt8(xb + row * CDIM + kt * 32 + quad * 8);
      } else {
        bf16x8 z;
#pragma unroll
        for (int j = 0; j < 8; ++j) z[j] = bits2bf(0);
        a_x[mt][kt] = z;
      }
    }
  }

  uint32_t qreg[2][6][2];  // q strip (pre-scaled) kept in registers, packed bf16
#pragma unroll
  for (int nt = 0; nt < 18; ++nt) {
    bf16x8 bw[3];
#pragma unroll
    for (int kt = 0; kt < 3; ++kt)
      bw[kt] = *(const bf16x8*)(qkv_wp + (((nt * 3 + kt) * 4 + quad) * 16 + l16) * 8);
    float bn = qkv_b[nt * 16 + l16];
#pragma unroll
    for (int mt = 0; mt < 2; ++mt) {
      f32x4 acc = {0.f, 0.f, 0.f, 0.f};
#pragma unroll
      for (int kt = 0; kt < 3; ++kt)
        acc = __builtin_amdgcn_mfma_f32_16x16x32_bf16(a_x[mt][kt], bw[kt], acc, 0, 0, 0);
      if (nt < 6) {  // q: fold softmax scale in here
        uint16_t h4[4];
#pragma unroll
        for (int i = 0; i < 4; ++i) h4[i] = f2bfbits((acc[i] + bn) * scale);
        qreg[mt][nt][0] = (uint32_t)h4[0] | ((uint32_t)h4[1] << 16);
        qreg[mt][nt][1] = (uint32_t)h4[2] | ((uint32_t)h4[3] << 16);
      } else if (nt < 12) {  // k, row-major; only real tokens stored
        int colb = (nt - 6) * 16 + l16;
#pragma unroll
        for (int i = 0; i < 4; ++i) {
          int row = rowbase + mt * 16 + quad * 4 + i;
          if (row < NTOK) k_lds[row * LDK + colb] = f2bf(acc[i] + bn);
        }
      } else {  // v, transposed: 4 consecutive tokens -> one 8B store
        int d = (nt - 12) * 16 + l16;
        int t0 = rowbase + mt * 16 + quad * 4;
        if (t0 < 112) {
          uint16_t h4[4];
#pragma unroll
          for (int i = 0; i < 4; ++i) h4[i] = f2bfbits(acc[i] + bn);
          uint2 pk;
          pk.x = (uint32_t)h4[0] | ((uint32_t)h4[1] << 16);
          pk.y = (uint32_t)h4[2] | ((uint32_t)h4[3] << 16);
          *(uint2*)&vT[d * LDV + t0] = pk;
        }
      }
    }
  }
  __syncthreads();

  // ---------------- attention, head-by-head ----------------
  float rsum[2][4];
  f32x4 oacc[2][2];

#pragma unroll
  for (int h = 0; h < 3; ++h) {
    // q strip (this head's 32 cols) -> per-wave scratch, D-layout -> row-major
#pragma unroll
    for (int mt = 0; mt < 2; ++mt)
#pragma unroll
      for (int nth = 0; nth < 2; ++nth) {
        uint32_t w0 = qreg[mt][2 * h + nth][0];
        uint32_t w1 = qreg[mt][2 * h + nth][1];
        int lr = mt * 16 + quad * 4;
        int cc = nth * 16 + l16;
        myscr[(lr + 0) * LDSCR + cc] = bits2bf((uint16_t)(w0 & 0xffffu));
        myscr[(lr + 1) * LDSCR + cc] = bits2bf((uint16_t)(w0 >> 16));
        myscr[(lr + 2) * LDSCR + cc] = bits2bf((uint16_t)(w1 & 0xffffu));
        myscr[(lr + 3) * LDSCR + cc] = bits2bf((uint16_t)(w1 >> 16));
      }
    asm volatile("s_waitcnt lgkmcnt(0)" ::: "memory");  // wave-local visibility
    bf16x8 aq[2];
#pragma unroll
    for (int mt = 0; mt < 2; ++mt)
      aq[mt] = *(bf16x8*)&myscr[(mt * 16 + l16) * LDSCR + quad * 8];

    // scores: S = q @ k^T, K=32 -> one MFMA per tile; S lives in regs.
    // nt=6 reads k_lds rows 98..111 -> overflow into vT (finite, masked).
    f32x4 sacc[2][7];
#pragma unroll
    for (int nt = 0; nt < 7; ++nt) {
      int tok = nt * 16 + l16;
      bf16x8 bk = *(bf16x8*)&k_lds[tok * LDK + h * 32 + quad * 8];
#pragma unroll
      for (int mt = 0; mt < 2; ++mt) {
        f32x4 z = {0.f, 0.f, 0.f, 0.f};
        sacc[mt][nt] = __builtin_amdgcn_mfma_f32_16x16x32_bf16(aq[mt], bk, z, 0, 0, 0);
      }
    }

    // softmax per row (row = 16 lanes of one quad x 7 regs); bias is a single
    // coalesced f32 load from the precomputed dense table.
#pragma unroll
    for (int mt = 0; mt < 2; ++mt)
#pragma unroll
      for (int i = 0; i < 4; ++i) {
        int row = rowbase + mt * 16 + quad * 4 + i;  // <=127; bias rows>=98 are 0
        float mx = -1e30f;
#pragma unroll
        for (int nt = 0; nt < 7; ++nt) {
          int col = nt * 16 + l16;
          float s = (col < NTOK)
                        ? sacc[mt][nt][i] + bias_full[(h * 128 + row) * 112 + col]
                        : -1e30f;
          sacc[mt][nt][i] = s;
          mx = fmaxf(mx, s);
        }
#pragma unroll
        for (int d2 = 1; d2 < 16; d2 <<= 1) mx = fmaxf(mx, __shfl_xor(mx, d2));
        float sum = 0.f;
#pragma unroll
        for (int nt = 0; nt < 7; ++nt) {
          float p = __expf(sacc[mt][nt][i] - mx);
          sacc[mt][nt][i] = p;
          sum += p;
        }
#pragma unroll
        for (int d2 = 1; d2 < 16; d2 <<= 1) sum += __shfl_xor(sum, d2);
        rsum[mt][i] = 1.f / sum;
      }

    // PV: out_h = P @ v_h ; P chunks through scratch (D-layout -> A-layout)
#pragma unroll
    for (int mt = 0; mt < 2; ++mt)
#pragma unroll
      for (int nh = 0; nh < 2; ++nh) {
        f32x4 z = {0.f, 0.f, 0.f, 0.f};
        oacc[mt][nh] = z;
      }
#pragma unroll
    for (int kt2 = 0; kt2 < 4; ++kt2) {
#pragma unroll
      for (int half = 0; half < 2; ++half) {
        int ntS = 2 * kt2 + half;
#pragma unroll
        for (int mt = 0; mt < 2; ++mt) {
          int lr = mt * 16 + quad * 4;
          int cc = half * 16 + l16;
#pragma unroll
          for (int i = 0; i < 4; ++i) {
            float v = (ntS < 7) ? sacc[mt][ntS][i] : 0.f;
            myscr[(lr + i) * LDSCR + cc] = f2bf(v);
          }
        }
      }
      asm volatile("s_waitcnt lgkmcnt(0)" ::: "memory");
#pragma unroll
      for (int mt = 0; mt < 2; ++mt) {
        bf16x8 ap = *(bf16x8*)&myscr[(mt * 16 + l16) * LDSCR + quad * 8];
#pragma unroll
        for (int nh = 0; nh < 2; ++nh) {
          // kt2=3,quad=3 reads spill past row end; P==0 there (finite garbage)
          bf16x8 bv = *(bf16x8*)&vT[(h * 32 + nh * 16 + l16) * LDV + kt2 * 32 + quad * 8];
          oacc[mt][nh] = __builtin_amdgcn_mfma_f32_16x16x32_bf16(ap, bv, oacc[mt][nh], 0, 0, 0);
        }
      }
    }

    // write out_h into the (dead) k_h columns after all waves finished scores.
    __syncthreads();
#pragma unroll
    for (int mt = 0; mt < 2; ++mt)
#pragma unroll
      for (int nh = 0; nh < 2; ++nh)
#pragma unroll
        for (int i = 0; i < 4; ++i) {
          int row = rowbase + mt * 16 + quad * 4 + i;
          if (row < NTOK)
            k_lds[row * LDK + h * 32 + nh * 16 + l16] =
                f2bf(oacc[mt][nh][i] * rsum[mt][i]);
        }
  }

  // ---------------- proj: [98x96] @ [96x96]^T + b ----------------
  bf16x8 ao[2][3];
#pragma unroll
  for (int mt = 0; mt < 2; ++mt) {
    int arow = rowbase + mt * 16 + l16;
    if (arow >= 112) arow = 0;  // garbage rows; results masked at store
#pragma unroll
    for (int kt = 0; kt < 3; ++kt)
      ao[mt][kt] = *(bf16x8*)&k_lds[arow * LDK + kt * 32 + quad * 8];
  }
  float* outb = out + (size_t)b * NTOK * CDIM;
#pragma unroll
  for (int nt = 0; nt < 6; ++nt) {
    bf16x8 bp[3];
#pragma unroll
    for (int kt = 0; kt < 3; ++kt)
      bp[kt] = *(const bf16x8*)(proj_wp + (((nt * 3 + kt) * 4 + quad) * 16 + l16) * 8);
    float pb = proj_b[nt * 16 + l16];
#pragma unroll
    for (int mt = 0; mt < 2; ++mt) {
      f32x4 acc = {0.f, 0.f, 0.f, 0.f};
#pragma unroll
      for (int kt = 0; kt < 3; ++kt)
        acc = __builtin_amdgcn_mfma_f32_16x16x32_bf16(ao[mt][kt], bp[kt], acc, 0, 0, 0);
#pragma unroll
      for (int i = 0; i < 4; ++i) {
        int row = rowbase + mt * 16 + quad * 4 + i;
        if (row < NTOK) outb[row * CDIM + nt * 16 + l16] = acc[i] + pb;
      }
    }
  }
}

extern "C" void kernel_launch(void* const* d_in, const int* in_sizes, int n_in,
                              void* d_out, int out_size, void* d_ws, size_t ws_size,
                              hipStream_t stream) {
  (void)n_in; (void)out_size; (void)ws_size;
  const float* x = (const float*)d_in[0];
  const float* qkv_w = (const float*)d_in[1];
  const float* qkv_b = (const float*)d_in[2];
  const float* proj_w = (const float*)d_in[3];
  const float* proj_b = (const float*)d_in[4];
  const float* bias_table = (const float*)d_in[5];
  const int* rel_index = (const int*)d_in[6];
  float* out = (float*)d_out;

  uint16_t* qkv_wp = (uint16_t*)d_ws;                    // 55296 B
  uint16_t* proj_wp = (uint16_t*)((char*)d_ws + 55296);  // 18432 B
  float* bias_full = (float*)((char*)d_ws + 73728);      // 172032 B

  precompute<<<dim3(64), dim3(256), 0, stream>>>(qkv_w, proj_w, bias_table,
                                                 rel_index, qkv_wp, proj_wp,
                                                 bias_full);
  int Bwin = in_sizes[0] / (NTOK * CDIM);
  wattn3d<<<dim3(Bwin), dim3(256), 0, stream>>>(x, qkv_b, proj_b, qkv_wp,
                                                proj_wp, bias_full, out);
}